// Round 18
// baseline (669.994 us; speedup 1.0000x reference)
//
#include <hip/hip_runtime.h>
#include <math.h>

typedef __attribute__((ext_vector_type(4))) float f32x4;
typedef __attribute__((ext_vector_type(8))) short short8;
typedef __attribute__((ext_vector_type(4))) short short4v;
typedef unsigned short u16;
typedef unsigned int u32;

#define T_TOKENS 65536
#define D_DIM    512
#define H_DIM    2048
#define O_DIM    512
#define E_NUM    8
#define CAP      8192

// ---- workspace layout (bytes) ----
static constexpr size_t OFF_COUNTS = 0;            // 8 ints
static constexpr size_t OFF_SELC   = 64;           // 8 ints
static constexpr size_t OFF_BNDC   = 128;          // 8 ints
static constexpr size_t OFF_PROC   = 192;          // T ints
static constexpr size_t OFF_HIST   = OFF_PROC + (size_t)T_TOKENS * 4;          // E*65536 uints (2MB)
static constexpr size_t CTRL_BYTES = OFF_HIST + (size_t)E_NUM * 65536 * 4;     // zeroed per launch
static constexpr size_t OFF_THR    = CTRL_BYTES;                               // 8 ints
static constexpr size_t OFF_REM    = OFF_THR + 64;                             // 8 ints
static constexpr size_t OFF_INV    = OFF_REM + 64;                             // 2T u32
static constexpr size_t OFF_CANDW  = OFF_INV + (size_t)T_TOKENS * 2 * 4;
static constexpr size_t OFF_CANDS  = OFF_CANDW + (size_t)E_NUM * T_TOKENS * 4; // +2MB
static constexpr size_t OFF_SELTOK = OFF_CANDS + (size_t)E_NUM * T_TOKENS * 4; // +2MB
static constexpr size_t OFF_SELW   = OFF_SELTOK + (size_t)E_NUM * CAP * 4;     // +256KB
static constexpr size_t OFF_LOG    = OFF_SELW + (size_t)E_NUM * CAP * 4;       // +256KB, 4MB region
static constexpr size_t OFF_BNDS   = OFF_LOG;                                  // 1MB (overlaps logits; logits dead before emit)
static constexpr size_t OFF_BNDW   = OFF_LOG + (size_t)E_NUM * CAP * 4 * 4;    // 1MB
static constexpr size_t OFF_XNB    = OFF_LOG + (size_t)T_TOKENS * E_NUM * 8;   // +4MB
static constexpr size_t OFF_W1T    = OFF_XNB + (size_t)T_TOKENS * D_DIM * 2;   // +64MB
static constexpr size_t OFF_W2T    = OFF_W1T + (size_t)E_NUM * D_DIM * H_DIM * 2; // +16MB
static constexpr size_t OFF_H      = OFF_W2T + (size_t)E_NUM * H_DIM * O_DIM * 2; // +16MB
static constexpr size_t OFF_FC2OUT = OFF_H + (size_t)E_NUM * CAP * H_DIM * 2;     // +256MB
static constexpr size_t NEED_BIG     = OFF_FC2OUT;                                 // ~365MB
static constexpr size_t NEED_COMBINE = OFF_FC2OUT + (size_t)E_NUM * CAP * O_DIM * 2; // ~430MB

__device__ __forceinline__ u16 f2b(float f) {            // f32 -> bf16 RNE
    unsigned u = __float_as_uint(f);
    unsigned r = (u + 0x7FFFu + ((u >> 16) & 1u)) >> 16;
    return (u16)r;
}
__device__ __forceinline__ float b2f(u16 b) {
    return __uint_as_float(((unsigned)b) << 16);
}
__device__ __forceinline__ u32 f2b_pack(float lo, float hi) {
    return (u32)f2b(lo) | ((u32)f2b(hi) << 16);
}

// tanh-form GELU (branch-free, ~8 VALU ops). Max |err| vs exact ~1e-3 (below bf16 noise of h).
__device__ __forceinline__ float gelu_fast(float x) {
    float x2 = x * x;
    float arg = x * fmaf(0.0713548162726f, x2, 1.59576912161f);
    float t = __expf(arg);
    float r = __builtin_amdgcn_rcpf(t + 1.0f);
    return x * (1.0f - r);
}

#define AS1 __attribute__((address_space(1)))
#define AS3 __attribute__((address_space(3)))

// ---------------- LayerNorm + fp64 logits (grid-stride, float2 loads, packed bf16 stores) -------
__global__ __launch_bounds__(256) void ln_kernel(
    const float* __restrict__ x, const float* __restrict__ gamma,
    const float* __restrict__ beta, const float* __restrict__ Wg,
    u16* __restrict__ xnb, double* __restrict__ logits)
{
    __shared__ float sWg[E_NUM * D_DIM];
    for (int i = threadIdx.x; i < E_NUM * D_DIM; i += 256) sWg[i] = Wg[i];
    __syncthreads();

    const int wave = threadIdx.x >> 6, lane = threadIdx.x & 63;

    for (int it = 0; it < 16; ++it) {
        const int t = blockIdx.x * 64 + it * 4 + wave;
        const float2* xr2 = (const float2*)(x + (size_t)t * D_DIM);

        float2 xv[4];
        #pragma unroll
        for (int i = 0; i < 4; i++) xv[i] = xr2[i * 64 + lane];

        double s = 0.0;
        #pragma unroll
        for (int i = 0; i < 4; i++) s += (double)xv[i].x + (double)xv[i].y;
        #pragma unroll
        for (int o = 32; o > 0; o >>= 1) s += __shfl_xor(s, o);
        double mu = s / 512.0;

        double v = 0.0;
        #pragma unroll
        for (int i = 0; i < 4; i++) {
            double d0 = (double)xv[i].x - mu, d1 = (double)xv[i].y - mu;
            v += d0 * d0 + d1 * d1;
        }
        #pragma unroll
        for (int o = 32; o > 0; o >>= 1) v += __shfl_xor(v, o);
        double rstd = 1.0 / sqrt(v / 512.0 + 1e-5);

        float xnf[8];
        u32* xno = (u32*)(xnb + (size_t)t * D_DIM);
        #pragma unroll
        for (int i = 0; i < 4; i++) {
            float2 g2 = ((const float2*)gamma)[i * 64 + lane];
            float2 b2v = ((const float2*)beta)[i * 64 + lane];
            double xd0 = ((double)xv[i].x - mu) * rstd * (double)g2.x + (double)b2v.x;
            double xd1 = ((double)xv[i].y - mu) * rstd * (double)g2.y + (double)b2v.y;
            xnf[2 * i]     = (float)xd0;
            xnf[2 * i + 1] = (float)xd1;
            xno[i * 64 + lane] = f2b_pack(xnf[2 * i], xnf[2 * i + 1]);
        }

        double p[E_NUM];
        #pragma unroll
        for (int e = 0; e < E_NUM; e++) p[e] = 0.0;
        #pragma unroll
        for (int i = 0; i < 4; i++) {
            int c = i * 128 + lane * 2;
            double xd0 = (double)xnf[2 * i];
            double xd1 = (double)xnf[2 * i + 1];
            #pragma unroll
            for (int e = 0; e < E_NUM; e++)
                p[e] += xd0 * (double)sWg[e * D_DIM + c] + xd1 * (double)sWg[e * D_DIM + c + 1];
        }
        #pragma unroll
        for (int o = 32; o > 0; o >>= 1) {
            #pragma unroll
            for (int e = 0; e < E_NUM; e++) p[e] += __shfl_xor(p[e], o);
        }
        if (lane < 8) {
            double vv = p[0];
            #pragma unroll
            for (int e = 1; e < 8; e++) if (lane == e) vv = p[e];
            logits[(size_t)t * 8 + lane] = vv;
        }
    }
}

// ---------------- gate: softmax + top2 + normalize + 16b-prefix histogram ----------------
__global__ __launch_bounds__(256) void gate_kernel(
    const double* __restrict__ logits, const float* __restrict__ noise,
    const float* __restrict__ bg,
    int* __restrict__ counts, float* __restrict__ cand_w, int* __restrict__ cand_slot,
    unsigned int* __restrict__ hist)
{
    __shared__ int lcnt[E_NUM], lbase[E_NUM];
    if (threadIdx.x < E_NUM) lcnt[threadIdx.x] = 0;
    __syncthreads();
    const int t = blockIdx.x * 256 + threadIdx.x;

    double l[E_NUM], m = -1e300;
    #pragma unroll
    for (int e = 0; e < E_NUM; e++) {
        l[e] = logits[(size_t)t * 8 + e] + (double)bg[e] + 0.125 * (double)noise[(size_t)t * 8 + e];
        if (l[e] > m) m = l[e];
    }
    double sum = 0.0, g[E_NUM];
    #pragma unroll
    for (int e = 0; e < E_NUM; e++) { g[e] = exp(l[e] - m); sum += g[e]; }
    double inv = 1.0 / sum;
    #pragma unroll
    for (int e = 0; e < E_NUM; e++) g[e] *= inv;

    double v1 = -1.0; int i1 = 0;
    #pragma unroll
    for (int e = 0; e < E_NUM; e++) if (g[e] > v1) { v1 = g[e]; i1 = e; }
    double v2 = -1.0; int i2 = 0;
    #pragma unroll
    for (int e = 0; e < E_NUM; e++) if (e != i1 && g[e] > v2) { v2 = g[e]; i2 = e; }

    double denom = v1 + v2 + 1e-20;
    float w1 = (float)(v1 / denom);
    float w2 = (float)(v2 / denom);

    atomicAdd(&hist[(size_t)i1 * 65536 + ((~__float_as_uint(w1)) >> 16)], 1u);
    atomicAdd(&hist[(size_t)i2 * 65536 + ((~__float_as_uint(w2)) >> 16)], 1u);

    int p1 = atomicAdd(&lcnt[i1], 1);
    int p2 = atomicAdd(&lcnt[i2], 1);
    __syncthreads();
    if (threadIdx.x < E_NUM) lbase[threadIdx.x] = atomicAdd(&counts[threadIdx.x], lcnt[threadIdx.x]);
    __syncthreads();
    cand_w[(size_t)i1 * T_TOKENS + lbase[i1] + p1] = w1;
    cand_slot[(size_t)i1 * T_TOKENS + lbase[i1] + p1] = 2 * t;
    cand_w[(size_t)i2 * T_TOKENS + lbase[i2] + p2] = w2;
    cand_slot[(size_t)i2 * T_TOKENS + lbase[i2] + p2] = 2 * t + 1;
}

// ---------------- scan: find 16-bit threshold bin + residual need per expert ----------------
__global__ __launch_bounds__(1024) void scan_kernel(
    const unsigned int* __restrict__ hist, const int* __restrict__ counts,
    int* __restrict__ thr16, int* __restrict__ rem)
{
    const int e = blockIdx.x;
    const int n = counts[e];
    if (n <= CAP) {
        if (threadIdx.x == 0) { thr16[e] = 65536; rem[e] = 0; }
        return;
    }
    const unsigned int* h = hist + (size_t)e * 65536;
    __shared__ unsigned int part[1024];
    const int tid = threadIdx.x;
    unsigned int own = 0;
    const int base = tid * 64;
    #pragma unroll 8
    for (int i = 0; i < 64; i++) own += h[base + i];
    part[tid] = own;
    __syncthreads();
    for (int off = 1; off < 1024; off <<= 1) {
        unsigned int v = (tid >= off) ? part[tid - off] : 0u;
        __syncthreads();
        part[tid] += v;
        __syncthreads();
    }
    unsigned int incl = part[tid];
    unsigned int excl = incl - own;
    const unsigned int need = CAP;
    if (excl < need && incl >= need) {
        unsigned int cum = excl;
        for (int i = 0; i < 64; i++) {
            unsigned int hv = h[base + i];
            if (cum + hv >= need) { thr16[e] = base + i; rem[e] = (int)(need - cum); break; }
            cum += hv;
        }
    }
}

// ---------------- emit: select below-threshold candidates, collect boundary bin ----------------
__global__ __launch_bounds__(256) void emit_kernel(
    const int* __restrict__ counts, const float* __restrict__ cand_w,
    const int* __restrict__ cand_slot, const int* __restrict__ thr16,
    int* __restrict__ sel_count, int* __restrict__ sel_tok, float* __restrict__ sel_w,
    int* __restrict__ bnd_count, int* __restrict__ bnd_slot, float* __restrict__ bnd_w,
    int* __restrict__ processed, u32* __restrict__ inv)
{
    const int e = blockIdx.y;
    const int n = counts[e];
    const int thr = thr16[e];
    const float* cw = cand_w + (size_t)e * T_TOKENS;
    const int* cs = cand_slot + (size_t)e * T_TOKENS;
    for (int i = blockIdx.x * 256 + threadIdx.x; i < n; i += gridDim.x * 256) {
        float w = cw[i];
        int slot = cs[i];
        int p16 = (int)((~__float_as_uint(w)) >> 16);
        if (p16 < thr) {
            int pos = atomicAdd(&sel_count[e], 1);
            sel_tok[e * CAP + pos] = slot >> 1;
            sel_w[e * CAP + pos]  = w;
            processed[slot >> 1] = 1;
            inv[slot] = ((u32)e << 16) | (u32)pos;
        } else if (p16 == thr) {
            int bpos = atomicAdd(&bnd_count[e], 1);
            bnd_slot[(size_t)e * CAP * 4 + bpos] = slot;
            bnd_w[(size_t)e * CAP * 4 + bpos]   = w;
        }
    }
}

// ---------------- boundary: exact rank among boundary-bin candidates ----------------
__global__ __launch_bounds__(256) void boundary_kernel(
    const int* __restrict__ bnd_count, const int* __restrict__ bnd_slot,
    const float* __restrict__ bnd_w, const int* __restrict__ rem,
    int* __restrict__ sel_count, int* __restrict__ sel_tok, float* __restrict__ sel_w,
    int* __restrict__ processed, u32* __restrict__ inv)
{
    const int e = blockIdx.x;
    const int r = rem[e];
    if (r == 0) return;
    const int nb = bnd_count[e];
    const int* bs = bnd_slot + (size_t)e * CAP * 4;
    const float* bw = bnd_w + (size_t)e * CAP * 4;
    for (int i = threadIdx.x; i < nb; i += 256) {
        unsigned long long ki = (((unsigned long long)(~__float_as_uint(bw[i]))) << 32) | (unsigned int)bs[i];
        int rank = 0;
        for (int j = 0; j < nb; j++) {
            unsigned long long kj = (((unsigned long long)(~__float_as_uint(bw[j]))) << 32) | (unsigned int)bs[j];
            rank += (kj < ki);
        }
        if (rank < r) {
            int pos = atomicAdd(&sel_count[e], 1);
            sel_tok[e * CAP + pos] = bs[i] >> 1;
            sel_w[e * CAP + pos]  = bw[i];
            processed[bs[i] >> 1] = 1;
            inv[bs[i]] = ((u32)e << 16) | (u32)pos;
        }
    }
}

// ---------------- fused weight convert: z<8 -> W1 [512x2048], z>=8 -> W2 [2048x512] -------------
__global__ __launch_bounds__(256) void convert_all_kernel(
    const float* __restrict__ W1, u16* __restrict__ W1t,
    const float* __restrict__ W2, u16* __restrict__ W2t)
{
    __shared__ float tile[64][65];
    int e, K, N, k0, n0;
    const float* W;
    u16* Wt;
    if (blockIdx.z < E_NUM) {
        e = blockIdx.z; K = D_DIM; N = H_DIM; W = W1; Wt = W1t;
        n0 = blockIdx.x * 64; k0 = blockIdx.y * 64;                 // x:32, y:8
    } else {
        e = blockIdx.z - E_NUM; K = H_DIM; N = O_DIM; W = W2; Wt = W2t;
        n0 = (blockIdx.x & 7) * 64;                                  // 8 n-tiles
        k0 = (blockIdx.y * 4 + (blockIdx.x >> 3)) * 64;              // 32 k-tiles
    }
    const float* We = W + (size_t)e * K * N;
    u16* Wte = Wt + (size_t)e * N * K;
    const int tx = threadIdx.x & 63, ty = threadIdx.x >> 6;
    #pragma unroll
    for (int r = 0; r < 64; r += 4)
        tile[ty + r][tx] = We[(size_t)(k0 + ty + r) * N + n0 + tx];
    __syncthreads();
    #pragma unroll
    for (int r = 0; r < 64; r += 4) {
        int nn = ty + r;
        Wte[(size_t)(n0 + nn) * K + k0 + tx] = f2b(tile[tx][nn]);
    }
}

// ---------------- fallback: out = processed ? 0 : xn ----------------
__global__ __launch_bounds__(256) void init_out_kernel(
    const u16* __restrict__ xnb, const int* __restrict__ processed, float* __restrict__ out)
{
    size_t i = (size_t)blockIdx.x * 256 + threadIdx.x;
    int t = (int)(i >> 7);
    float4 v; v.x = 0.f; v.y = 0.f; v.z = 0.f; v.w = 0.f;
    if (!processed[t]) {
        const u16* xp = xnb + (i << 2);
        v.x = b2f(xp[0]); v.y = b2f(xp[1]); v.z = b2f(xp[2]); v.w = b2f(xp[3]);
    }
    ((float4*)out)[i] = v;
}

// ---------------- combine: out[t] = sum of pre-weighted bf16 expert rows, else passthrough xn ----
__global__ __launch_bounds__(256) void combine_kernel(
    const u16* __restrict__ fc2out, const u32* __restrict__ inv,
    const u16* __restrict__ xnb, float* __restrict__ out)
{
    size_t i = (size_t)blockIdx.x * 256 + threadIdx.x;
    int t = (int)(i >> 7);
    int c4 = (int)(i & 127);
    u32 a = inv[2 * t], b = inv[2 * t + 1];
    float4 v; v.x = 0.f; v.y = 0.f; v.z = 0.f; v.w = 0.f;
    bool any = false;
    if (a != 0xFFFFFFFFu) {
        const u16* p = fc2out + ((size_t)(a >> 16) * CAP + (a & 0xFFFFu)) * O_DIM + c4 * 4;
        short4v pv = *(const short4v*)p;
        v.x += b2f((u16)pv.x); v.y += b2f((u16)pv.y); v.z += b2f((u16)pv.z); v.w += b2f((u16)pv.w);
        any = true;
    }
    if (b != 0xFFFFFFFFu) {
        const u16* p = fc2out + ((size_t)(b >> 16) * CAP + (b & 0xFFFFu)) * O_DIM + c4 * 4;
        short4v pv = *(const short4v*)p;
        v.x += b2f((u16)pv.x); v.y += b2f((u16)pv.y); v.z += b2f((u16)pv.z); v.w += b2f((u16)pv.w);
        any = true;
    }
    if (!any) {
        const u16* xp = xnb + (i << 2);
        v.x = b2f(xp[0]); v.y = b2f(xp[1]); v.z = b2f(xp[2]); v.w = b2f(xp[3]);
    }
    ((float4*)out)[i] = v;
}

// ---------------- bf16 MFMA GEMM: 128x128 tile, 256 threads (4 waves), 32KB LDS total,
// half-K (K=32) double buffer, SINGLE-BARRIER step (R18): per step
//   { vmcnt(0); barrier; issue stage(nxt); ds_read(cur); MFMA }
// Hazard proof: stage(nxt) at step h targets buf[(h+1)&1]; its last readers (step h-1)
// all passed barrier h before any wave issues the stage (write-after-read safe). Reads of
// buf[cur] are safe: each wave's vmcnt(0) drains its own step-(h-1) loads before barrier h,
// so after the barrier the whole buffer is landed. Halves barrier count vs R15-R17.
// Swizzle: both-sides involution for 64B rows (store src slot (t&3)^((t>>3)&3), read lg^((ar>>1)&3)).
// EPI 0: h = bf16(gelu_fast(acc+bias))   EPI 2: atomicAdd (fallback)   EPI 3: bf16 fc2out
template<int GATHER, int EPI, int MERGED, int KT>
__global__ __launch_bounds__(256, 4) void moe_gemm_kernel(
    const u16* __restrict__ Abase, const u16* __restrict__ Btbase,
    const float* __restrict__ biasbase,
    const int* __restrict__ sel_tok, const float* __restrict__ sel_w,
    const int* __restrict__ sel_count, int e_arg, int N,
    size_t a_estride, size_t h_estride,
    u16* __restrict__ h_out, u16* __restrict__ out16, float* __restrict__ outf)
{
    __shared__ u16 sA[2 * 128 * 32];   // 16KB (two 8KB halves)
    __shared__ u16 sB[2 * 128 * 32];   // 16KB

    const int e = MERGED ? blockIdx.z : e_arg;
    const int selc = sel_count[e];
    const int row0 = blockIdx.x * 128;
    if (row0 >= selc) return;
    const int n0 = blockIdx.y * 128;

    const u16* A = Abase + (size_t)e * a_estride;
    const u16* Bt = Btbase + (size_t)e * (size_t)N * KT;
    const float* bias = biasbase + (size_t)e * N;
    const int* sel_tok_e = sel_tok + (size_t)e * CAP;
    const float* sel_w_e = sel_w + (size_t)e * CAP;

    const int t = threadIdx.x;            // 0..255
    const int lane = t & 63;
    const int w = t >> 6;                 // 0..3
    const int wm = (w >> 1) * 64;         // wave M base
    const int wn = (w & 1) * 64;          // wave N base
    const int lr = lane & 15;
    const int lg = lane >> 4;

    const int srow_lo = t >> 2;                             // 0..63
    const u32 swz = (u32)(((t & 3) ^ ((t >> 3) & 3)) * 8);  // u16 elems within half-row

    u32 aoff[2];
    #pragma unroll
    for (int i = 0; i < 2; i++) {
        int r = row0 + i * 64 + srow_lo;
        int gr;
        if (GATHER) gr = (r < selc) ? sel_tok_e[r] : 0;
        else        gr = r;
        aoff[i] = (u32)gr * (u32)KT + swz;
    }
    u32 boff[2];
    #pragma unroll
    for (int i = 0; i < 2; i++) {
        int nn = n0 + i * 64 + srow_lo;
        boff[i] = (u32)nn * (u32)KT + swz;
    }

    f32x4 acc[4][4] = {};
    constexpr int NH = KT / 32;

    // prologue: stage half 0 into buffer 0
    #pragma unroll
    for (int i = 0; i < 2; i++)
        __builtin_amdgcn_global_load_lds((const AS1 void*)(A + aoff[i]),
                                         (AS3 void*)&sA[0 * 4096 + i * 2048 + t * 8], 16, 0, 0);
    #pragma unroll
    for (int i = 0; i < 2; i++)
        __builtin_amdgcn_global_load_lds((const AS1 void*)(Bt + boff[i]),
                                         (AS3 void*)&sB[0 * 4096 + i * 2048 + t * 8], 16, 0, 0);

    for (int kh = 0; kh < NH; ++kh) {
        const int cur = kh & 1;

        asm volatile("s_waitcnt vmcnt(0)" ::: "memory");   // own loads for buf[cur] landed
        __builtin_amdgcn_s_barrier();                       // all waves' loads landed; prev readers done

        if (kh + 1 < NH) {                                  // issue next-half loads into buf[cur^1]
            const int nxt = cur ^ 1;
            const int ko = (kh + 1) * 32;
            #pragma unroll
            for (int i = 0; i < 2; i++)
                __builtin_amdgcn_global_load_lds((const AS1 void*)(A + aoff[i] + ko),
                                                 (AS3 void*)&sA[nxt * 4096 + i * 2048 + t * 8], 16, 0, 0);
            #pragma unroll
            for (int i = 0; i < 2; i++)
                __builtin_amdgcn_global_load_lds((const AS1 void*)(Bt + boff[i] + ko),
                                                 (AS3 void*)&sB[nxt * 4096 + i * 2048 + t * 8], 16, 0, 0);
        }

        const u16* sAc = &sA[cur * 4096];
        const u16* sBc = &sB[cur * 4096];
        __builtin_amdgcn_s_setprio(1);
        {
            short8 bf[4];
            #pragma unroll
            for (int n = 0; n < 4; n++) {
                int br = wn + n * 16 + lr;
                bf[n] = *(const short8*)&sBc[br * 32 + ((lg ^ ((br >> 1) & 3)) * 8)];
            }
            #pragma unroll
            for (int m = 0; m < 4; m++) {
                int ar = wm + m * 16 + lr;
                short8 af = *(const short8*)&sAc[ar * 32 + ((lg ^ ((ar >> 1) & 3)) * 8)];
                #pragma unroll
                for (int n = 0; n < 4; n++)
                    acc[m][n] = __builtin_amdgcn_mfma_f32_16x16x32_bf16(af, bf[n], acc[m][n], 0, 0, 0);
            }
        }
        __builtin_amdgcn_s_setprio(0);
    }

    if (EPI == 0) {
        u16* hO = h_out + (size_t)e * h_estride;
        #pragma unroll
        for (int m = 0; m < 4; m++) {
            int row = row0 + wm + m * 16 + lg * 4;
            #pragma unroll
            for (int n = 0; n < 4; n++) {
                int col = n0 + wn + n * 16 + lr;
                float bb = bias[col];
                #pragma unroll
                for (int r = 0; r < 4; r++) {
                    float vv = acc[m][n][r] + bb;
                    hO[(size_t)(row + r) * N + col] = f2b(gelu_fast(vv));
                }
            }
        }
    } else if (EPI == 3) {
        #pragma unroll
        for (int m = 0; m < 4; m++) {
            int row = row0 + wm + m * 16 + lg * 4;
            #pragma unroll
            for (int r = 0; r < 4; r++) {
                int rr = row + r;
                if (rr < selc) {
                    float wgt = sel_w_e[rr];
                    u16* orow = out16 + ((size_t)e * CAP + rr) * O_DIM;
                    #pragma unroll
                    for (int n = 0; n < 4; n++) {
                        int col = n0 + wn + n * 16 + lr;
                        orow[col] = f2b(wgt * (acc[m][n][r] + bias[col]));
                    }
                }
            }
        }
    } else {
        #pragma unroll
        for (int m = 0; m < 4; m++) {
            int row = row0 + wm + m * 16 + lg * 4;
            #pragma unroll
            for (int r = 0; r < 4; r++) {
                int rr = row + r;
                if (rr < selc) {
                    int tok = sel_tok_e[rr];
                    float wgt = sel_w_e[rr];
                    float* orow = outf + (size_t)tok * O_DIM;
                    #pragma unroll
                    for (int n = 0; n < 4; n++) {
                        int col = n0 + wn + n * 16 + lr;
                        atomicAdd(&orow[col], wgt * (acc[m][n][r] + bias[col]));
                    }
                }
            }
        }
    }
}

extern "C" void kernel_launch(void* const* d_in, const int* in_sizes, int n_in,
                              void* d_out, int out_size, void* d_ws, size_t ws_size,
                              hipStream_t stream) {
    const float* x     = (const float*)d_in[0];
    const float* noise = (const float*)d_in[1];
    const float* gamma = (const float*)d_in[2];
    const float* beta  = (const float*)d_in[3];
    const float* Wg    = (const float*)d_in[4];
    const float* bg    = (const float*)d_in[5];
    const float* W1    = (const float*)d_in[6];
    const float* b1    = (const float*)d_in[7];
    const float* W2    = (const float*)d_in[8];
    const float* b2    = (const float*)d_in[9];
    float* out = (float*)d_out;

    char* ws = (char*)d_ws;
    int*    counts    = (int*)(ws + OFF_COUNTS);
    int*    sel_count = (int*)(ws + OFF_SELC);
    int*    bnd_count = (int*)(ws + OFF_BNDC);
    int*    processed = (int*)(ws + OFF_PROC);
    unsigned int* hist = (unsigned int*)(ws + OFF_HIST);
    int*    thr16     = (int*)(ws + OFF_THR);
    int*    rem       = (int*)(ws + OFF_REM);
    u32*    inv       = (u32*)(ws + OFF_INV);
    float*  cand_w    = (float*)(ws + OFF_CANDW);
    int*    cand_slot = (int*)(ws + OFF_CANDS);
    int*    sel_tok   = (int*)(ws + OFF_SELTOK);
    float*  sel_w     = (float*)(ws + OFF_SELW);
    double* logits    = (double*)(ws + OFF_LOG);
    int*    bnd_slot  = (int*)(ws + OFF_BNDS);
    float*  bnd_w     = (float*)(ws + OFF_BNDW);
    u16*    xnb       = (u16*)(ws + OFF_XNB);
    u16*    W1t       = (u16*)(ws + OFF_W1T);
    u16*    W2t       = (u16*)(ws + OFF_W2T);
    u16*    h         = (u16*)(ws + OFF_H);
    u16*    fc2out    = (u16*)(ws + OFF_FC2OUT);

    const bool use_combine = (ws_size >= NEED_COMBINE);

    hipMemsetAsync(ws, 0, CTRL_BYTES, stream);
    if (use_combine)
        hipMemsetAsync(ws + OFF_INV, 0xFF, (size_t)T_TOKENS * 2 * 4, stream);
    hipMemsetAsync((char*)d_out + (size_t)T_TOKENS * O_DIM * 4, 0, 4, stream);  // aux_loss = 0

    convert_all_kernel<<<dim3(32, 8, 16), 256, 0, stream>>>(W1, W1t, W2, W2t);

    ln_kernel<<<T_TOKENS / 64, 256, 0, stream>>>(x, gamma, beta, Wg, xnb, logits);
    gate_kernel<<<T_TOKENS / 256, 256, 0, stream>>>(logits, noise, bg, counts, cand_w, cand_slot, hist);
    scan_kernel<<<E_NUM, 1024, 0, stream>>>(hist, counts, thr16, rem);
    emit_kernel<<<dim3(64, E_NUM), 256, 0, stream>>>(counts, cand_w, cand_slot, thr16,
                                                     sel_count, sel_tok, sel_w,
                                                     bnd_count, bnd_slot, bnd_w, processed, inv);
    boundary_kernel<<<E_NUM, 256, 0, stream>>>(bnd_count, bnd_slot, bnd_w, rem,
                                               sel_count, sel_tok, sel_w, processed, inv);

    if (use_combine) {
        moe_gemm_kernel<1, 0, 1, D_DIM><<<dim3(CAP / 128, H_DIM / 128, E_NUM), 256, 0, stream>>>(
            xnb, W1t, b1, sel_tok, sel_w, sel_count, 0, H_DIM,
            0, (size_t)CAP * H_DIM, h, nullptr, nullptr);
        moe_gemm_kernel<0, 3, 1, H_DIM><<<dim3(CAP / 128, O_DIM / 128, E_NUM), 256, 0, stream>>>(
            h, W2t, b2, sel_tok, sel_w, sel_count, 0, O_DIM,
            (size_t)CAP * H_DIM, 0, nullptr, fc2out, nullptr);
        combine_kernel<<<(T_TOKENS * O_DIM / 4) / 256, 256, 0, stream>>>(fc2out, inv, xnb, out);
    } else if (ws_size >= NEED_BIG) {
        init_out_kernel<<<(T_TOKENS * O_DIM / 4) / 256, 256, 0, stream>>>(xnb, processed, out);
        moe_gemm_kernel<1, 0, 1, D_DIM><<<dim3(CAP / 128, H_DIM / 128, E_NUM), 256, 0, stream>>>(
            xnb, W1t, b1, sel_tok, sel_w, sel_count, 0, H_DIM,
            0, (size_t)CAP * H_DIM, h, nullptr, nullptr);
        moe_gemm_kernel<0, 2, 1, H_DIM><<<dim3(CAP / 128, O_DIM / 128, E_NUM), 256, 0, stream>>>(
            h, W2t, b2, sel_tok, sel_w, sel_count, 0, O_DIM,
            (size_t)CAP * H_DIM, 0, nullptr, nullptr, out);
    } else {
        init_out_kernel<<<(T_TOKENS * O_DIM / 4) / 256, 256, 0, stream>>>(xnb, processed, out);
        for (int e = 0; e < E_NUM; e++) {
            moe_gemm_kernel<1, 0, 0, D_DIM><<<dim3(CAP / 128, H_DIM / 128), 256, 0, stream>>>(
                xnb, W1t, b1, sel_tok, sel_w, sel_count, e, H_DIM,
                0, 0, h, nullptr, nullptr);
            moe_gemm_kernel<0, 2, 0, H_DIM><<<dim3(CAP / 128, O_DIM / 128), 256, 0, stream>>>(
                h, W2t, b2, sel_tok, sel_w, sel_count, e, O_DIM,
                0, 0, nullptr, nullptr, out);
        }
    }
}

// Round 19
// 667.904 us; speedup vs baseline: 1.0031x; 1.0031x over previous
//
#include <hip/hip_runtime.h>
#include <math.h>

typedef __attribute__((ext_vector_type(4))) float f32x4;
typedef __attribute__((ext_vector_type(8))) short short8;
typedef __attribute__((ext_vector_type(4))) short short4v;
typedef unsigned short u16;
typedef unsigned int u32;

#define T_TOKENS 65536
#define D_DIM    512
#define H_DIM    2048
#define O_DIM    512
#define E_NUM    8
#define CAP      8192

// ---- workspace layout (bytes) ----
static constexpr size_t OFF_COUNTS = 0;            // 8 ints
static constexpr size_t OFF_SELC   = 64;           // 8 ints
static constexpr size_t OFF_BNDC   = 128;          // 8 ints
static constexpr size_t OFF_PROC   = 192;          // T ints
static constexpr size_t OFF_HIST   = OFF_PROC + (size_t)T_TOKENS * 4;          // E*65536 uints (2MB)
static constexpr size_t CTRL_BYTES = OFF_HIST + (size_t)E_NUM * 65536 * 4;     // zeroed per launch
static constexpr size_t OFF_THR    = CTRL_BYTES;                               // 8 ints
static constexpr size_t OFF_REM    = OFF_THR + 64;                             // 8 ints
static constexpr size_t OFF_INV    = OFF_REM + 64;                             // 2T u32
static constexpr size_t OFF_CANDW  = OFF_INV + (size_t)T_TOKENS * 2 * 4;
static constexpr size_t OFF_CANDS  = OFF_CANDW + (size_t)E_NUM * T_TOKENS * 4; // +2MB
static constexpr size_t OFF_SELTOK = OFF_CANDS + (size_t)E_NUM * T_TOKENS * 4; // +2MB
static constexpr size_t OFF_SELW   = OFF_SELTOK + (size_t)E_NUM * CAP * 4;     // +256KB
static constexpr size_t OFF_LOG    = OFF_SELW + (size_t)E_NUM * CAP * 4;       // +256KB, 4MB region
static constexpr size_t OFF_BNDS   = OFF_LOG;                                  // 1MB (overlaps logits; logits dead before emit)
static constexpr size_t OFF_BNDW   = OFF_LOG + (size_t)E_NUM * CAP * 4 * 4;    // 1MB
static constexpr size_t OFF_XNB    = OFF_LOG + (size_t)T_TOKENS * E_NUM * 8;   // +4MB
static constexpr size_t OFF_W1T    = OFF_XNB + (size_t)T_TOKENS * D_DIM * 2;   // +64MB
static constexpr size_t OFF_W2T    = OFF_W1T + (size_t)E_NUM * D_DIM * H_DIM * 2; // +16MB
static constexpr size_t OFF_H      = OFF_W2T + (size_t)E_NUM * H_DIM * O_DIM * 2; // +16MB
static constexpr size_t OFF_FC2OUT = OFF_H + (size_t)E_NUM * CAP * H_DIM * 2;     // +256MB
static constexpr size_t NEED_BIG     = OFF_FC2OUT;                                 // ~365MB
static constexpr size_t NEED_COMBINE = OFF_FC2OUT + (size_t)E_NUM * CAP * O_DIM * 2; // ~430MB

__device__ __forceinline__ u16 f2b(float f) {            // f32 -> bf16 RNE
    unsigned u = __float_as_uint(f);
    unsigned r = (u + 0x7FFFu + ((u >> 16) & 1u)) >> 16;
    return (u16)r;
}
__device__ __forceinline__ float b2f(u16 b) {
    return __uint_as_float(((unsigned)b) << 16);
}
__device__ __forceinline__ u32 f2b_pack(float lo, float hi) {
    return (u32)f2b(lo) | ((u32)f2b(hi) << 16);
}

// tanh-form GELU (branch-free, ~8 VALU ops). Max |err| vs exact ~1e-3 (below bf16 noise of h).
__device__ __forceinline__ float gelu_fast(float x) {
    float x2 = x * x;
    float arg = x * fmaf(0.0713548162726f, x2, 1.59576912161f);
    float t = __expf(arg);
    float r = __builtin_amdgcn_rcpf(t + 1.0f);
    return x * (1.0f - r);
}

#define AS1 __attribute__((address_space(1)))
#define AS3 __attribute__((address_space(3)))

// ---------------- LayerNorm + fp64 logits (grid-stride, float2 loads, packed bf16 stores) -------
__global__ __launch_bounds__(256) void ln_kernel(
    const float* __restrict__ x, const float* __restrict__ gamma,
    const float* __restrict__ beta, const float* __restrict__ Wg,
    u16* __restrict__ xnb, double* __restrict__ logits)
{
    __shared__ float sWg[E_NUM * D_DIM];
    for (int i = threadIdx.x; i < E_NUM * D_DIM; i += 256) sWg[i] = Wg[i];
    __syncthreads();

    const int wave = threadIdx.x >> 6, lane = threadIdx.x & 63;

    for (int it = 0; it < 16; ++it) {
        const int t = blockIdx.x * 64 + it * 4 + wave;
        const float2* xr2 = (const float2*)(x + (size_t)t * D_DIM);

        float2 xv[4];
        #pragma unroll
        for (int i = 0; i < 4; i++) xv[i] = xr2[i * 64 + lane];

        double s = 0.0;
        #pragma unroll
        for (int i = 0; i < 4; i++) s += (double)xv[i].x + (double)xv[i].y;
        #pragma unroll
        for (int o = 32; o > 0; o >>= 1) s += __shfl_xor(s, o);
        double mu = s / 512.0;

        double v = 0.0;
        #pragma unroll
        for (int i = 0; i < 4; i++) {
            double d0 = (double)xv[i].x - mu, d1 = (double)xv[i].y - mu;
            v += d0 * d0 + d1 * d1;
        }
        #pragma unroll
        for (int o = 32; o > 0; o >>= 1) v += __shfl_xor(v, o);
        double rstd = 1.0 / sqrt(v / 512.0 + 1e-5);

        float xnf[8];
        u32* xno = (u32*)(xnb + (size_t)t * D_DIM);
        #pragma unroll
        for (int i = 0; i < 4; i++) {
            float2 g2 = ((const float2*)gamma)[i * 64 + lane];
            float2 b2v = ((const float2*)beta)[i * 64 + lane];
            double xd0 = ((double)xv[i].x - mu) * rstd * (double)g2.x + (double)b2v.x;
            double xd1 = ((double)xv[i].y - mu) * rstd * (double)g2.y + (double)b2v.y;
            xnf[2 * i]     = (float)xd0;
            xnf[2 * i + 1] = (float)xd1;
            xno[i * 64 + lane] = f2b_pack(xnf[2 * i], xnf[2 * i + 1]);
        }

        double p[E_NUM];
        #pragma unroll
        for (int e = 0; e < E_NUM; e++) p[e] = 0.0;
        #pragma unroll
        for (int i = 0; i < 4; i++) {
            int c = i * 128 + lane * 2;
            double xd0 = (double)xnf[2 * i];
            double xd1 = (double)xnf[2 * i + 1];
            #pragma unroll
            for (int e = 0; e < E_NUM; e++)
                p[e] += xd0 * (double)sWg[e * D_DIM + c] + xd1 * (double)sWg[e * D_DIM + c + 1];
        }
        #pragma unroll
        for (int o = 32; o > 0; o >>= 1) {
            #pragma unroll
            for (int e = 0; e < E_NUM; e++) p[e] += __shfl_xor(p[e], o);
        }
        if (lane < 8) {
            double vv = p[0];
            #pragma unroll
            for (int e = 1; e < 8; e++) if (lane == e) vv = p[e];
            logits[(size_t)t * 8 + lane] = vv;
        }
    }
}

// ---------------- gate: softmax + top2 + normalize + 16b-prefix histogram ----------------
__global__ __launch_bounds__(256) void gate_kernel(
    const double* __restrict__ logits, const float* __restrict__ noise,
    const float* __restrict__ bg,
    int* __restrict__ counts, float* __restrict__ cand_w, int* __restrict__ cand_slot,
    unsigned int* __restrict__ hist)
{
    __shared__ int lcnt[E_NUM], lbase[E_NUM];
    if (threadIdx.x < E_NUM) lcnt[threadIdx.x] = 0;
    __syncthreads();
    const int t = blockIdx.x * 256 + threadIdx.x;

    double l[E_NUM], m = -1e300;
    #pragma unroll
    for (int e = 0; e < E_NUM; e++) {
        l[e] = logits[(size_t)t * 8 + e] + (double)bg[e] + 0.125 * (double)noise[(size_t)t * 8 + e];
        if (l[e] > m) m = l[e];
    }
    double sum = 0.0, g[E_NUM];
    #pragma unroll
    for (int e = 0; e < E_NUM; e++) { g[e] = exp(l[e] - m); sum += g[e]; }
    double inv = 1.0 / sum;
    #pragma unroll
    for (int e = 0; e < E_NUM; e++) g[e] *= inv;

    double v1 = -1.0; int i1 = 0;
    #pragma unroll
    for (int e = 0; e < E_NUM; e++) if (g[e] > v1) { v1 = g[e]; i1 = e; }
    double v2 = -1.0; int i2 = 0;
    #pragma unroll
    for (int e = 0; e < E_NUM; e++) if (e != i1 && g[e] > v2) { v2 = g[e]; i2 = e; }

    double denom = v1 + v2 + 1e-20;
    float w1 = (float)(v1 / denom);
    float w2 = (float)(v2 / denom);

    atomicAdd(&hist[(size_t)i1 * 65536 + ((~__float_as_uint(w1)) >> 16)], 1u);
    atomicAdd(&hist[(size_t)i2 * 65536 + ((~__float_as_uint(w2)) >> 16)], 1u);

    int p1 = atomicAdd(&lcnt[i1], 1);
    int p2 = atomicAdd(&lcnt[i2], 1);
    __syncthreads();
    if (threadIdx.x < E_NUM) lbase[threadIdx.x] = atomicAdd(&counts[threadIdx.x], lcnt[threadIdx.x]);
    __syncthreads();
    cand_w[(size_t)i1 * T_TOKENS + lbase[i1] + p1] = w1;
    cand_slot[(size_t)i1 * T_TOKENS + lbase[i1] + p1] = 2 * t;
    cand_w[(size_t)i2 * T_TOKENS + lbase[i2] + p2] = w2;
    cand_slot[(size_t)i2 * T_TOKENS + lbase[i2] + p2] = 2 * t + 1;
}

// ---------------- scan: find 16-bit threshold bin + residual need per expert ----------------
__global__ __launch_bounds__(1024) void scan_kernel(
    const unsigned int* __restrict__ hist, const int* __restrict__ counts,
    int* __restrict__ thr16, int* __restrict__ rem)
{
    const int e = blockIdx.x;
    const int n = counts[e];
    if (n <= CAP) {
        if (threadIdx.x == 0) { thr16[e] = 65536; rem[e] = 0; }
        return;
    }
    const unsigned int* h = hist + (size_t)e * 65536;
    __shared__ unsigned int part[1024];
    const int tid = threadIdx.x;
    unsigned int own = 0;
    const int base = tid * 64;
    #pragma unroll 8
    for (int i = 0; i < 64; i++) own += h[base + i];
    part[tid] = own;
    __syncthreads();
    for (int off = 1; off < 1024; off <<= 1) {
        unsigned int v = (tid >= off) ? part[tid - off] : 0u;
        __syncthreads();
        part[tid] += v;
        __syncthreads();
    }
    unsigned int incl = part[tid];
    unsigned int excl = incl - own;
    const unsigned int need = CAP;
    if (excl < need && incl >= need) {
        unsigned int cum = excl;
        for (int i = 0; i < 64; i++) {
            unsigned int hv = h[base + i];
            if (cum + hv >= need) { thr16[e] = base + i; rem[e] = (int)(need - cum); break; }
            cum += hv;
        }
    }
}

// ---------------- emit: select below-threshold candidates, collect boundary bin ----------------
__global__ __launch_bounds__(256) void emit_kernel(
    const int* __restrict__ counts, const float* __restrict__ cand_w,
    const int* __restrict__ cand_slot, const int* __restrict__ thr16,
    int* __restrict__ sel_count, int* __restrict__ sel_tok, float* __restrict__ sel_w,
    int* __restrict__ bnd_count, int* __restrict__ bnd_slot, float* __restrict__ bnd_w,
    int* __restrict__ processed, u32* __restrict__ inv)
{
    const int e = blockIdx.y;
    const int n = counts[e];
    const int thr = thr16[e];
    const float* cw = cand_w + (size_t)e * T_TOKENS;
    const int* cs = cand_slot + (size_t)e * T_TOKENS;
    for (int i = blockIdx.x * 256 + threadIdx.x; i < n; i += gridDim.x * 256) {
        float w = cw[i];
        int slot = cs[i];
        int p16 = (int)((~__float_as_uint(w)) >> 16);
        if (p16 < thr) {
            int pos = atomicAdd(&sel_count[e], 1);
            sel_tok[e * CAP + pos] = slot >> 1;
            sel_w[e * CAP + pos]  = w;
            processed[slot >> 1] = 1;
            inv[slot] = ((u32)e << 16) | (u32)pos;
        } else if (p16 == thr) {
            int bpos = atomicAdd(&bnd_count[e], 1);
            bnd_slot[(size_t)e * CAP * 4 + bpos] = slot;
            bnd_w[(size_t)e * CAP * 4 + bpos]   = w;
        }
    }
}

// ---------------- boundary: exact rank among boundary-bin candidates ----------------
__global__ __launch_bounds__(256) void boundary_kernel(
    const int* __restrict__ bnd_count, const int* __restrict__ bnd_slot,
    const float* __restrict__ bnd_w, const int* __restrict__ rem,
    int* __restrict__ sel_count, int* __restrict__ sel_tok, float* __restrict__ sel_w,
    int* __restrict__ processed, u32* __restrict__ inv)
{
    const int e = blockIdx.x;
    const int r = rem[e];
    if (r == 0) return;
    const int nb = bnd_count[e];
    const int* bs = bnd_slot + (size_t)e * CAP * 4;
    const float* bw = bnd_w + (size_t)e * CAP * 4;
    for (int i = threadIdx.x; i < nb; i += 256) {
        unsigned long long ki = (((unsigned long long)(~__float_as_uint(bw[i]))) << 32) | (unsigned int)bs[i];
        int rank = 0;
        for (int j = 0; j < nb; j++) {
            unsigned long long kj = (((unsigned long long)(~__float_as_uint(bw[j]))) << 32) | (unsigned int)bs[j];
            rank += (kj < ki);
        }
        if (rank < r) {
            int pos = atomicAdd(&sel_count[e], 1);
            sel_tok[e * CAP + pos] = bs[i] >> 1;
            sel_w[e * CAP + pos]  = bw[i];
            processed[bs[i] >> 1] = 1;
            inv[bs[i]] = ((u32)e << 16) | (u32)pos;
        }
    }
}

// ---------------- fused weight convert: z<8 -> W1 [512x2048], z>=8 -> W2 [2048x512] -------------
__global__ __launch_bounds__(256) void convert_all_kernel(
    const float* __restrict__ W1, u16* __restrict__ W1t,
    const float* __restrict__ W2, u16* __restrict__ W2t)
{
    __shared__ float tile[64][65];
    int e, K, N, k0, n0;
    const float* W;
    u16* Wt;
    if (blockIdx.z < E_NUM) {
        e = blockIdx.z; K = D_DIM; N = H_DIM; W = W1; Wt = W1t;
        n0 = blockIdx.x * 64; k0 = blockIdx.y * 64;                 // x:32, y:8
    } else {
        e = blockIdx.z - E_NUM; K = H_DIM; N = O_DIM; W = W2; Wt = W2t;
        n0 = (blockIdx.x & 7) * 64;                                  // 8 n-tiles
        k0 = (blockIdx.y * 4 + (blockIdx.x >> 3)) * 64;              // 32 k-tiles
    }
    const float* We = W + (size_t)e * K * N;
    u16* Wte = Wt + (size_t)e * N * K;
    const int tx = threadIdx.x & 63, ty = threadIdx.x >> 6;
    #pragma unroll
    for (int r = 0; r < 64; r += 4)
        tile[ty + r][tx] = We[(size_t)(k0 + ty + r) * N + n0 + tx];
    __syncthreads();
    #pragma unroll
    for (int r = 0; r < 64; r += 4) {
        int nn = ty + r;
        Wte[(size_t)(n0 + nn) * K + k0 + tx] = f2b(tile[tx][nn]);
    }
}

// ---------------- fallback: out = processed ? 0 : xn ----------------
__global__ __launch_bounds__(256) void init_out_kernel(
    const u16* __restrict__ xnb, const int* __restrict__ processed, float* __restrict__ out)
{
    size_t i = (size_t)blockIdx.x * 256 + threadIdx.x;
    int t = (int)(i >> 7);
    float4 v; v.x = 0.f; v.y = 0.f; v.z = 0.f; v.w = 0.f;
    if (!processed[t]) {
        const u16* xp = xnb + (i << 2);
        v.x = b2f(xp[0]); v.y = b2f(xp[1]); v.z = b2f(xp[2]); v.w = b2f(xp[3]);
    }
    ((float4*)out)[i] = v;
}

// ---------------- combine: out[t] = sum of pre-weighted bf16 expert rows, else passthrough xn ----
__global__ __launch_bounds__(256) void combine_kernel(
    const u16* __restrict__ fc2out, const u32* __restrict__ inv,
    const u16* __restrict__ xnb, float* __restrict__ out)
{
    size_t i = (size_t)blockIdx.x * 256 + threadIdx.x;
    int t = (int)(i >> 7);
    int c4 = (int)(i & 127);
    u32 a = inv[2 * t], b = inv[2 * t + 1];
    float4 v; v.x = 0.f; v.y = 0.f; v.z = 0.f; v.w = 0.f;
    bool any = false;
    if (a != 0xFFFFFFFFu) {
        const u16* p = fc2out + ((size_t)(a >> 16) * CAP + (a & 0xFFFFu)) * O_DIM + c4 * 4;
        short4v pv = *(const short4v*)p;
        v.x += b2f((u16)pv.x); v.y += b2f((u16)pv.y); v.z += b2f((u16)pv.z); v.w += b2f((u16)pv.w);
        any = true;
    }
    if (b != 0xFFFFFFFFu) {
        const u16* p = fc2out + ((size_t)(b >> 16) * CAP + (b & 0xFFFFu)) * O_DIM + c4 * 4;
        short4v pv = *(const short4v*)p;
        v.x += b2f((u16)pv.x); v.y += b2f((u16)pv.y); v.z += b2f((u16)pv.z); v.w += b2f((u16)pv.w);
        any = true;
    }
    if (!any) {
        const u16* xp = xnb + (i << 2);
        v.x = b2f(xp[0]); v.y = b2f(xp[1]); v.z = b2f(xp[2]); v.w = b2f(xp[3]);
    }
    ((float4*)out)[i] = v;
}

// ---------------- bf16 MFMA GEMM: 256x128 block tile, 4 waves, 128x64 PER WAVE (R19):
// LDS-intensity restructure: 12 ds_read_b128 per 32 MFMA per K=32 step (was 8 per 16) ->
// per-CU LDS:MFMA pipe ratio drops 5:1 -> ~3.7:1 even at 2 blocks/CU.
// acc 8x4 f32x4 = 128 regs + ~70 arch ~= 198 <= 256 cap from launch_bounds(256,2)
// (explicit 2 waves/SIMD: allocator NOT squeezed below need - R8 lesson inverted).
// LDS 48KB/block (A 2x256x32, B 2x128x32) -> 2 blocks/CU. Single-barrier step (R18):
//   { vmcnt(0); barrier; stage(nxt); ds_read(cur); MFMA }  - hazard proof as R18.
// Swizzle: both-sides involution for 64B rows (store src slot (t&3)^((t>>3)&3), read lg^((ar>>1)&3)).
// EPI 0: h = bf16(gelu_fast(acc+bias))   EPI 2: atomicAdd (fallback)   EPI 3: bf16 fc2out
template<int GATHER, int EPI, int MERGED, int KT>
__global__ __launch_bounds__(256, 2) void moe_gemm_kernel(
    const u16* __restrict__ Abase, const u16* __restrict__ Btbase,
    const float* __restrict__ biasbase,
    const int* __restrict__ sel_tok, const float* __restrict__ sel_w,
    const int* __restrict__ sel_count, int e_arg, int N,
    size_t a_estride, size_t h_estride,
    u16* __restrict__ h_out, u16* __restrict__ out16, float* __restrict__ outf)
{
    __shared__ u16 sA[2 * 256 * 32];   // 32KB (two 16KB halves)
    __shared__ u16 sB[2 * 128 * 32];   // 16KB

    const int e = MERGED ? blockIdx.z : e_arg;
    const int selc = sel_count[e];
    const int row0 = blockIdx.x * 256;
    if (row0 >= selc) return;
    const int n0 = blockIdx.y * 128;

    const u16* A = Abase + (size_t)e * a_estride;
    const u16* Bt = Btbase + (size_t)e * (size_t)N * KT;
    const float* bias = biasbase + (size_t)e * N;
    const int* sel_tok_e = sel_tok + (size_t)e * CAP;
    const float* sel_w_e = sel_w + (size_t)e * CAP;

    const int t = threadIdx.x;            // 0..255
    const int lane = t & 63;
    const int w = t >> 6;                 // 0..3
    const int wm = (w >> 1) * 128;        // wave M base (two 128-row halves)
    const int wn = (w & 1) * 64;          // wave N base (two 64-col halves)
    const int lr = lane & 15;
    const int lg = lane >> 4;

    const int srow_lo = t >> 2;                             // 0..63
    const u32 swz = (u32)(((t & 3) ^ ((t >> 3) & 3)) * 8);  // u16 elems within half-row

    u32 aoff[4];
    #pragma unroll
    for (int i = 0; i < 4; i++) {
        int r = row0 + i * 64 + srow_lo;
        int gr;
        if (GATHER) gr = (r < selc) ? sel_tok_e[r] : 0;
        else        gr = r;
        aoff[i] = (u32)gr * (u32)KT + swz;
    }
    u32 boff[2];
    #pragma unroll
    for (int i = 0; i < 2; i++) {
        int nn = n0 + i * 64 + srow_lo;
        boff[i] = (u32)nn * (u32)KT + swz;
    }

    f32x4 acc[8][4] = {};
    constexpr int NH = KT / 32;

    // prologue: stage half 0 into buffer 0 (A: 4 insts of 64 rows; B: 2 insts)
    #pragma unroll
    for (int i = 0; i < 4; i++)
        __builtin_amdgcn_global_load_lds((const AS1 void*)(A + aoff[i]),
                                         (AS3 void*)&sA[0 * 8192 + i * 2048 + t * 8], 16, 0, 0);
    #pragma unroll
    for (int i = 0; i < 2; i++)
        __builtin_amdgcn_global_load_lds((const AS1 void*)(Bt + boff[i]),
                                         (AS3 void*)&sB[0 * 4096 + i * 2048 + t * 8], 16, 0, 0);

    for (int kh = 0; kh < NH; ++kh) {
        const int cur = kh & 1;

        asm volatile("s_waitcnt vmcnt(0)" ::: "memory");   // own loads for buf[cur] landed
        __builtin_amdgcn_s_barrier();                       // all waves' loads landed; prev readers done

        if (kh + 1 < NH) {                                  // issue next-half loads into buf[cur^1]
            const int nxt = cur ^ 1;
            const int ko = (kh + 1) * 32;
            #pragma unroll
            for (int i = 0; i < 4; i++)
                __builtin_amdgcn_global_load_lds((const AS1 void*)(A + aoff[i] + ko),
                                                 (AS3 void*)&sA[nxt * 8192 + i * 2048 + t * 8], 16, 0, 0);
            #pragma unroll
            for (int i = 0; i < 2; i++)
                __builtin_amdgcn_global_load_lds((const AS1 void*)(Bt + boff[i] + ko),
                                                 (AS3 void*)&sB[nxt * 4096 + i * 2048 + t * 8], 16, 0, 0);
        }

        const u16* sAc = &sA[cur * 8192];
        const u16* sBc = &sB[cur * 4096];
        __builtin_amdgcn_s_setprio(1);
        {
            short8 bf[4];
            #pragma unroll
            for (int n = 0; n < 4; n++) {
                int br = wn + n * 16 + lr;
                bf[n] = *(const short8*)&sBc[br * 32 + ((lg ^ ((br >> 1) & 3)) * 8)];
            }
            #pragma unroll
            for (int m = 0; m < 8; m++) {
                int ar = wm + m * 16 + lr;
                short8 af = *(const short8*)&sAc[ar * 32 + ((lg ^ ((ar >> 1) & 3)) * 8)];
                #pragma unroll
                for (int n = 0; n < 4; n++)
                    acc[m][n] = __builtin_amdgcn_mfma_f32_16x16x32_bf16(af, bf[n], acc[m][n], 0, 0, 0);
            }
        }
        __builtin_amdgcn_s_setprio(0);
    }

    if (EPI == 0) {
        u16* hO = h_out + (size_t)e * h_estride;
        #pragma unroll
        for (int m = 0; m < 8; m++) {
            int row = row0 + wm + m * 16 + lg * 4;
            #pragma unroll
            for (int n = 0; n < 4; n++) {
                int col = n0 + wn + n * 16 + lr;
                float bb = bias[col];
                #pragma unroll
                for (int r = 0; r < 4; r++) {
                    float vv = acc[m][n][r] + bb;
                    hO[(size_t)(row + r) * N + col] = f2b(gelu_fast(vv));
                }
            }
        }
    } else if (EPI == 3) {
        #pragma unroll
        for (int m = 0; m < 8; m++) {
            int row = row0 + wm + m * 16 + lg * 4;
            #pragma unroll
            for (int r = 0; r < 4; r++) {
                int rr = row + r;
                if (rr < selc) {
                    float wgt = sel_w_e[rr];
                    u16* orow = out16 + ((size_t)e * CAP + rr) * O_DIM;
                    #pragma unroll
                    for (int n = 0; n < 4; n++) {
                        int col = n0 + wn + n * 16 + lr;
                        orow[col] = f2b(wgt * (acc[m][n][r] + bias[col]));
                    }
                }
            }
        }
    } else {
        #pragma unroll
        for (int m = 0; m < 8; m++) {
            int row = row0 + wm + m * 16 + lg * 4;
            #pragma unroll
            for (int r = 0; r < 4; r++) {
                int rr = row + r;
                if (rr < selc) {
                    int tok = sel_tok_e[rr];
                    float wgt = sel_w_e[rr];
                    float* orow = outf + (size_t)tok * O_DIM;
                    #pragma unroll
                    for (int n = 0; n < 4; n++) {
                        int col = n0 + wn + n * 16 + lr;
                        atomicAdd(&orow[col], wgt * (acc[m][n][r] + bias[col]));
                    }
                }
            }
        }
    }
}

extern "C" void kernel_launch(void* const* d_in, const int* in_sizes, int n_in,
                              void* d_out, int out_size, void* d_ws, size_t ws_size,
                              hipStream_t stream) {
    const float* x     = (const float*)d_in[0];
    const float* noise = (const float*)d_in[1];
    const float* gamma = (const float*)d_in[2];
    const float* beta  = (const float*)d_in[3];
    const float* Wg    = (const float*)d_in[4];
    const float* bg    = (const float*)d_in[5];
    const float* W1    = (const float*)d_in[6];
    const float* b1    = (const float*)d_in[7];
    const float* W2    = (const float*)d_in[8];
    const float* b2    = (const float*)d_in[9];
    float* out = (float*)d_out;

    char* ws = (char*)d_ws;
    int*    counts    = (int*)(ws + OFF_COUNTS);
    int*    sel_count = (int*)(ws + OFF_SELC);
    int*    bnd_count = (int*)(ws + OFF_BNDC);
    int*    processed = (int*)(ws + OFF_PROC);
    unsigned int* hist = (unsigned int*)(ws + OFF_HIST);
    int*    thr16     = (int*)(ws + OFF_THR);
    int*    rem       = (int*)(ws + OFF_REM);
    u32*    inv       = (u32*)(ws + OFF_INV);
    float*  cand_w    = (float*)(ws + OFF_CANDW);
    int*    cand_slot = (int*)(ws + OFF_CANDS);
    int*    sel_tok   = (int*)(ws + OFF_SELTOK);
    float*  sel_w     = (float*)(ws + OFF_SELW);
    double* logits    = (double*)(ws + OFF_LOG);
    int*    bnd_slot  = (int*)(ws + OFF_BNDS);
    float*  bnd_w     = (float*)(ws + OFF_BNDW);
    u16*    xnb       = (u16*)(ws + OFF_XNB);
    u16*    W1t       = (u16*)(ws + OFF_W1T);
    u16*    W2t       = (u16*)(ws + OFF_W2T);
    u16*    h         = (u16*)(ws + OFF_H);
    u16*    fc2out    = (u16*)(ws + OFF_FC2OUT);

    const bool use_combine = (ws_size >= NEED_COMBINE);

    hipMemsetAsync(ws, 0, CTRL_BYTES, stream);
    if (use_combine)
        hipMemsetAsync(ws + OFF_INV, 0xFF, (size_t)T_TOKENS * 2 * 4, stream);
    hipMemsetAsync((char*)d_out + (size_t)T_TOKENS * O_DIM * 4, 0, 4, stream);  // aux_loss = 0

    convert_all_kernel<<<dim3(32, 8, 16), 256, 0, stream>>>(W1, W1t, W2, W2t);

    ln_kernel<<<T_TOKENS / 64, 256, 0, stream>>>(x, gamma, beta, Wg, xnb, logits);
    gate_kernel<<<T_TOKENS / 256, 256, 0, stream>>>(logits, noise, bg, counts, cand_w, cand_slot, hist);
    scan_kernel<<<E_NUM, 1024, 0, stream>>>(hist, counts, thr16, rem);
    emit_kernel<<<dim3(64, E_NUM), 256, 0, stream>>>(counts, cand_w, cand_slot, thr16,
                                                     sel_count, sel_tok, sel_w,
                                                     bnd_count, bnd_slot, bnd_w, processed, inv);
    boundary_kernel<<<E_NUM, 256, 0, stream>>>(bnd_count, bnd_slot, bnd_w, rem,
                                               sel_count, sel_tok, sel_w, processed, inv);

    if (use_combine) {
        moe_gemm_kernel<1, 0, 1, D_DIM><<<dim3(CAP / 256, H_DIM / 128, E_NUM), 256, 0, stream>>>(
            xnb, W1t, b1, sel_tok, sel_w, sel_count, 0, H_DIM,
            0, (size_t)CAP * H_DIM, h, nullptr, nullptr);
        moe_gemm_kernel<0, 3, 1, H_DIM><<<dim3(CAP / 256, O_DIM / 128, E_NUM), 256, 0, stream>>>(
            h, W2t, b2, sel_tok, sel_w, sel_count, 0, O_DIM,
            (size_t)CAP * H_DIM, 0, nullptr, fc2out, nullptr);
        combine_kernel<<<(T_TOKENS * O_DIM / 4) / 256, 256, 0, stream>>>(fc2out, inv, xnb, out);
    } else if (ws_size >= NEED_BIG) {
        init_out_kernel<<<(T_TOKENS * O_DIM / 4) / 256, 256, 0, stream>>>(xnb, processed, out);
        moe_gemm_kernel<1, 0, 1, D_DIM><<<dim3(CAP / 256, H_DIM / 128, E_NUM), 256, 0, stream>>>(
            xnb, W1t, b1, sel_tok, sel_w, sel_count, 0, H_DIM,
            0, (size_t)CAP * H_DIM, h, nullptr, nullptr);
        moe_gemm_kernel<0, 2, 1, H_DIM><<<dim3(CAP / 256, O_DIM / 128, E_NUM), 256, 0, stream>>>(
            h, W2t, b2, sel_tok, sel_w, sel_count, 0, O_DIM,
            (size_t)CAP * H_DIM, 0, nullptr, nullptr, out);
    } else {
        init_out_kernel<<<(T_TOKENS * O_DIM / 4) / 256, 256, 0, stream>>>(xnb, processed, out);
        for (int e = 0; e < E_NUM; e++) {
            moe_gemm_kernel<1, 0, 0, D_DIM><<<dim3(CAP / 256, H_DIM / 128), 256, 0, stream>>>(
                xnb, W1t, b1, sel_tok, sel_w, sel_count, e, H_DIM,
                0, 0, h, nullptr, nullptr);
            moe_gemm_kernel<0, 2, 0, H_DIM><<<dim3(CAP / 256, O_DIM / 128), 256, 0, stream>>>(
                h, W2t, b2, sel_tok, sel_w, sel_count, e, O_DIM,
                0, 0, nullptr, nullptr, out);
        }
    }
}